// Round 10
// baseline (284.446 us; speedup 1.0000x reference)
//
#include <hip/hip_runtime.h>

// GraphSAGE 2-layer + edge scorer, MI355X.
// R10: fusion round. (1) count/scan1/scan3 eliminated -- binsort builds
// rowstart from its own bucket records (LDS hist + scan); CSR build is now
// coarse-hist (fused into conv grid) -> 1-block cscan -> bin -> binsort2.
// (2) gather1 fused into gemm1: waves gather 16 node-means into LDS
// (stride 136 vs bank conflicts), then MFMA -- kills the 25.6 MB agg
// round-trip. 13 launches -> 9.
// Kept: scalar gather2 via wp-dot commute (R7), binned CSR build (R6),
// B-in-registers GEMMs (R5), mean(h1[src])@W2n == mean((h1@W2n)[src]).

#define NN 50000
#define EM 800000
#define EPOS 200000
#define ENEG 200000
#define NB 196            // coarse buckets: 196*256 >= NN
#define RPB 4096          // records per bin/coarse block
#define CBLK 196          // coarse-hist blocks: 196*4096 >= EM
#define MTILES 3125       // 50000 / 16 exactly
#define GEMM_GRID 512
#define XCONV_BLOCKS 6250 // NN*128/4/256

typedef __bf16 bf16;
typedef bf16 bf16x4 __attribute__((ext_vector_type(4)));
typedef bf16 bf16x8 __attribute__((ext_vector_type(8)));
typedef float floatx4 __attribute__((ext_vector_type(4)));
typedef unsigned long long u64;

// ---- workspace offsets ----
// int-word offsets:
#define I_CC   0             // 256 (coarse counts; memset 1 KB)
#define I_BOFF 256           // 512 (entries 0..NB)
#define I_CCUR 768           // 256
#define I_ROW  1024          // 50432 -> ends 51456
#define I_CSR  51456         // 800000 -> ends 851456
// byte offsets:
#define B_CREG 3405824       // 800000 * 8B (6.4 MB)
#define B_XB   9805824       // 6.4M bf16 (12.8 MB)
#define B_H1   22605824      // 12.8M bf16 (25.6 MB)
#define B_NV   48205824      // 50000 float4 (800 KB)
#define B_WT1  49005824      // 65536 bf16
#define B_WT2  49136896      // 65536 bf16
#define B_P    49267968      // 50176 fp32
#define B_Q    49468672      // 50176 fp32
// end ~49.7 MB

// fused conversions + coarse histogram.
// blocks [0,XCONV): x fp32->bf16; [XCONV,XCONV+256): weights;
// [XCONV+256, +CBLK): LDS coarse hist of mdst>>8 -> global atomics into cc.
__global__ __launch_bounds__(256) void convc_kernel(
    const float* __restrict__ x, bf16* __restrict__ xb,
    const float* __restrict__ W1s, const float* __restrict__ W1n,
    const float* __restrict__ W2n, const float* __restrict__ W2s,
    bf16* __restrict__ Wt1, bf16* __restrict__ Wt2,
    const int* __restrict__ mdst, int* __restrict__ cc) {
    if (blockIdx.x < XCONV_BLOCKS) {
        int i = blockIdx.x * 256 + threadIdx.x;
        float4 v = ((const float4*)x)[i];
        bf16x4 o;
        o[0] = (bf16)v.x; o[1] = (bf16)v.y; o[2] = (bf16)v.z; o[3] = (bf16)v.w;
        *(bf16x4*)(xb + (size_t)i * 4) = o;
    } else if (blockIdx.x < XCONV_BLOCKS + 256) {
        int i = (blockIdx.x - XCONV_BLOCKS) * 256 + threadIdx.x;
        int n = i >> 8, k = i & 255;
        float w1 = (k < 128) ? W1s[k * 256 + n] : W1n[(k - 128) * 256 + n];
        Wt1[i] = (bf16)w1;
        float w2 = (n < 128) ? W2n[k * 128 + n] : W2s[k * 128 + (n - 128)];
        Wt2[i] = (bf16)w2;
    } else {
        __shared__ int h[NB];
        int t = threadIdx.x;
        int cb = blockIdx.x - (XCONV_BLOCKS + 256);
        for (int i = t; i < NB; i += 256) h[i] = 0;
        __syncthreads();
        int e0 = cb * RPB;
        int nrec = EM - e0; if (nrec > RPB) nrec = RPB;
        for (int j = t; j < nrec; j += 256) atomicAdd(&h[mdst[e0 + j] >> 8], 1);
        __syncthreads();
        if (t < NB && h[t] > 0) atomicAdd(&cc[t], h[t]);
    }
}

// 1-block scan of the NB coarse counts -> boff (exclusive, +sentinel), ccur.
__global__ __launch_bounds__(256) void cscan_kernel(const int* __restrict__ cc,
                                                    int* __restrict__ boff,
                                                    int* __restrict__ ccur) {
    __shared__ int s[256];
    int t = threadIdx.x;
    s[t] = (t < NB) ? cc[t] : 0;
    __syncthreads();
    for (int o = 1; o < 256; o <<= 1) {
        int u = (t >= o) ? s[t - o] : 0;
        __syncthreads();
        s[t] += u;
        __syncthreads();
    }
    int excl = (t == 0) ? 0 : s[t - 1];
    if (t < NB) { boff[t] = excl; ccur[t] = excl; }
    if (t == 0) boff[NB] = EM;
}

// pass A: LDS-sort 4096 edges by coarse bucket (dst>>8), flush bucket-grouped
// 8B (src,dst) records into per-bucket regions of creg.
__global__ __launch_bounds__(256) void bin_kernel(const int* __restrict__ src,
                                                  const int* __restrict__ dst,
                                                  int* __restrict__ ccur,
                                                  u64* __restrict__ creg) {
    __shared__ int hist[NB];
    __shared__ int cnt2[NB];
    __shared__ int goff[NB];
    __shared__ int base[256];
    __shared__ u64 sorted[RPB];
    int t = threadIdx.x;
    int e0 = blockIdx.x * RPB;
    int nrec = EM - e0; if (nrec > RPB) nrec = RPB;

    for (int i = t; i < NB; i += 256) { hist[i] = 0; cnt2[i] = 0; }
    __syncthreads();

    int myb[RPB / 256];
    u64 myrec[RPB / 256];
#pragma unroll
    for (int j = 0; j < RPB / 256; ++j) {
        int idx = j * 256 + t;
        if (idx < nrec) {
            int s = src[e0 + idx], d = dst[e0 + idx];
            myb[j] = d >> 8;
            myrec[j] = ((u64)(unsigned)d << 32) | (unsigned)s;
            atomicAdd(&hist[myb[j]], 1);
        } else myb[j] = -1;
    }
    __syncthreads();

    base[t] = (t < NB) ? hist[t] : 0;
    __syncthreads();
    for (int o = 1; o < 256; o <<= 1) {
        int u = (t >= o) ? base[t - o] : 0;
        __syncthreads();
        base[t] += u;
        __syncthreads();
    }

    if (t < NB && hist[t] > 0) goff[t] = atomicAdd(&ccur[t], hist[t]);
#pragma unroll
    for (int j = 0; j < RPB / 256; ++j) {
        if (myb[j] >= 0) {
            int rk = atomicAdd(&cnt2[myb[j]], 1);
            sorted[base[myb[j]] - hist[myb[j]] + rk] = myrec[j];
        }
    }
    __syncthreads();

#pragma unroll
    for (int j = 0; j < RPB / 256; ++j) {
        int idx = j * 256 + t;
        if (idx < nrec) {
            u64 rec = sorted[idx];
            int b = (int)(rec >> 40);
            int exb = base[b] - hist[b];
            creg[(size_t)goff[b] + (idx - exb)] = rec;
        }
    }
}

// pass B: one block per bucket. Builds rowstart for its 256 nodes from its
// own records (LDS hist + scan) AND places edges into csr via LDS cursors.
__global__ __launch_bounds__(256) void binsort_kernel(
    const u64* __restrict__ creg, const int* __restrict__ boff,
    int* __restrict__ rowstart, int* __restrict__ csr) {
    __shared__ int lcnt[256];
    __shared__ int sc[256];
    __shared__ int lcur[256];
    int b = blockIdx.x, t = threadIdx.x;
    int beg = boff[b], end = boff[b + 1];
    lcnt[t] = 0;
    __syncthreads();
    for (int i = beg + t; i < end; i += 256) {
        int d = (int)(creg[i] >> 32);
        atomicAdd(&lcnt[d & 255], 1);
    }
    __syncthreads();
    sc[t] = lcnt[t];
    __syncthreads();
    for (int o = 1; o < 256; o <<= 1) {
        int u = (t >= o) ? sc[t - o] : 0;
        __syncthreads();
        sc[t] += u;
        __syncthreads();
    }
    int excl = beg + sc[t] - lcnt[t];
    int node = b * 256 + t;
    if (node < NN) rowstart[node] = excl;
    if (b == NB - 1 && t == 0) rowstart[NN] = EM;
    lcur[t] = excl;
    __syncthreads();
    for (int i = beg + t; i < end; i += 256) {
        u64 rec = creg[i];
        int d = (int)(rec >> 32);
        int pos = atomicAdd(&lcur[d & 255], 1);
        csr[pos] = (int)(rec & 0xffffffffu);
    }
}

// Fused gather1+gemm1: per 16-row tile, 4 waves gather the 16 node-means
// (wave per node, 4-edge ILP) into LDS, then h1 = relu([x|agg]@Wt1^T + b1).
__global__ __launch_bounds__(256) void ggemm1_kernel(
    const bf16* __restrict__ xb, const int* __restrict__ rowstart,
    const int* __restrict__ csr, const bf16* __restrict__ Wt,
    const float* __restrict__ b1, bf16* __restrict__ h1b) {
    __shared__ bf16 sAgg[16][136];   // stride 136 -> 2-way-max bank aliasing
    int w = threadIdx.x >> 6;
    int lane = threadIdx.x & 63;
    int r = lane & 15, quad = lane >> 4;
    int colbase = w * 64;

    bf16x8 bfr[4][8];
#pragma unroll
    for (int t = 0; t < 4; ++t)
#pragma unroll
        for (int kk = 0; kk < 8; ++kk)
            bfr[t][kk] = *(const bf16x8*)(Wt + (size_t)(colbase + t * 16 + r) * 256
                                          + kk * 32 + quad * 8);
    float bb[4];
#pragma unroll
    for (int t = 0; t < 4; ++t) bb[t] = b1[colbase + t * 16 + r];

    for (int tile = blockIdx.x; tile < MTILES; tile += GEMM_GRID) {
        int m0 = tile * 16;
        // gather phase: wave w handles tile-local nodes {w, 4+w, 8+w, 12+w}
#pragma unroll
        for (int jj = 0; jj < 4; ++jj) {
            int idx = jj * 4 + w;
            int node = m0 + idx;
            int beg = rowstart[node], end = rowstart[node + 1];
            int c = r * 8;
            float acc[8] = {0.f, 0.f, 0.f, 0.f, 0.f, 0.f, 0.f, 0.f};
            for (int i = beg + quad; i < end; i += 4) {
                int s = csr[i];
                bf16x8 v = *(const bf16x8*)(xb + (size_t)s * 128 + c);
#pragma unroll
                for (int u = 0; u < 8; ++u) acc[u] += (float)v[u];
            }
#pragma unroll
            for (int m = 16; m <= 32; m <<= 1)
#pragma unroll
                for (int u = 0; u < 8; ++u) acc[u] += __shfl_xor(acc[u], m);
            if (quad == 0) {
                int deg = end - beg;
                float inv = 1.0f / (float)(deg > 0 ? deg : 1);
                bf16x8 o;
#pragma unroll
                for (int u = 0; u < 8; ++u) o[u] = (bf16)(acc[u] * inv);
                *(bf16x8*)(&sAgg[idx][c]) = o;
            }
        }
        __syncthreads();
        // MFMA phase
        int row = m0 + r;
        bf16x8 a[8];
#pragma unroll
        for (int kk = 0; kk < 4; ++kk)
            a[kk] = *(const bf16x8*)(xb + (size_t)row * 128 + kk * 32 + quad * 8);
#pragma unroll
        for (int kk = 4; kk < 8; ++kk)
            a[kk] = *(const bf16x8*)(&sAgg[r][(kk - 4) * 32 + quad * 8]);
        floatx4 acc4[4];
#pragma unroll
        for (int t = 0; t < 4; ++t) acc4[t] = (floatx4){0.f, 0.f, 0.f, 0.f};
#pragma unroll
        for (int kk = 0; kk < 8; ++kk)
#pragma unroll
            for (int t = 0; t < 4; ++t)
                acc4[t] = __builtin_amdgcn_mfma_f32_16x16x32_bf16(a[kk], bfr[t][kk],
                                                                  acc4[t], 0, 0, 0);
        int mb = m0 + quad * 4;
#pragma unroll
        for (int t = 0; t < 4; ++t) {
            int col = colbase + t * 16 + r;
#pragma unroll
            for (int rr = 0; rr < 4; ++rr) {
                float v = acc4[t][rr] + bb[t];
                v = v > 0.f ? v : 0.f;
                h1b[(size_t)(mb + rr) * 256 + col] = (bf16)v;
            }
        }
        __syncthreads();   // protect sAgg before next tile's gather
    }
}

// Fused gemm2: nodev[n] = {zp, zq, ps, qs}; zp=(h1@W2n)[n].wp[:128] etc.
__global__ __launch_bounds__(256) void gemm2_kernel(
    const bf16* __restrict__ h1b, const bf16* __restrict__ Wt,
    const float* __restrict__ b2, const float* __restrict__ wp,
    float4* __restrict__ nodev) {
    __shared__ float lp[4][16];
    __shared__ float lq[4][16];
    int w = threadIdx.x >> 6;
    int lane = threadIdx.x & 63;
    int r = lane & 15, quad = lane >> 4;
    int colbase = w * 64;

    bf16x8 bfr[4][8];
#pragma unroll
    for (int t = 0; t < 4; ++t)
#pragma unroll
        for (int kk = 0; kk < 8; ++kk)
            bfr[t][kk] = *(const bf16x8*)(Wt + (size_t)(colbase + t * 16 + r) * 256
                                          + kk * 32 + quad * 8);
    float bb[4], wA[4], wB[4];
#pragma unroll
    for (int t = 0; t < 4; ++t) {
        int col = colbase + t * 16 + r;
        if (w < 2) {
            bb[t] = 0.f;
            wA[t] = wp[col];
            wB[t] = wp[128 + col];
        } else {
            int c2 = col - 128;
            bb[t] = b2[c2];
            wA[t] = wp[c2];
            wB[t] = wp[128 + c2];
        }
    }

    for (int tile = blockIdx.x; tile < MTILES; tile += GEMM_GRID) {
        int m0 = tile * 16;
        int row = m0 + r;
        bf16x8 a[8];
#pragma unroll
        for (int kk = 0; kk < 8; ++kk)
            a[kk] = *(const bf16x8*)(h1b + (size_t)row * 256 + kk * 32 + quad * 8);
        floatx4 acc[4];
#pragma unroll
        for (int t = 0; t < 4; ++t) acc[t] = (floatx4){0.f, 0.f, 0.f, 0.f};
#pragma unroll
        for (int kk = 0; kk < 8; ++kk)
#pragma unroll
            for (int t = 0; t < 4; ++t)
                acc[t] = __builtin_amdgcn_mfma_f32_16x16x32_bf16(a[kk], bfr[t][kk],
                                                                 acc[t], 0, 0, 0);
        float pacc[4], qacc[4];
#pragma unroll
        for (int rr = 0; rr < 4; ++rr) {
            float pr = 0.f, qr = 0.f;
#pragma unroll
            for (int t = 0; t < 4; ++t) {
                float v = acc[t][rr] + bb[t];
                pr += v * wA[t];
                qr += v * wB[t];
            }
            pacc[rr] = pr;
            qacc[rr] = qr;
        }
#pragma unroll
        for (int m = 1; m <= 8; m <<= 1) {
#pragma unroll
            for (int rr = 0; rr < 4; ++rr) {
                pacc[rr] += __shfl_xor(pacc[rr], m);
                qacc[rr] += __shfl_xor(qacc[rr], m);
            }
        }
        if (r == 0) {
#pragma unroll
            for (int rr = 0; rr < 4; ++rr) {
                lp[w][quad * 4 + rr] = pacc[rr];
                lq[w][quad * 4 + rr] = qacc[rr];
            }
        }
        __syncthreads();
        if (threadIdx.x < 16) {
            int rw = threadIdx.x;
            float4 o;
            o.x = lp[0][rw] + lp[1][rw];
            o.y = lq[0][rw] + lq[1][rw];
            o.z = lp[2][rw] + lp[3][rw];
            o.w = lq[2][rw] + lq[3][rw];
            nodev[m0 + rw] = o;
        }
        __syncthreads();
    }
}

// scalar gather: p[n] = ps[n] + mean(zp[src]); q likewise. nodev is 800 KB.
__global__ __launch_bounds__(256) void gather2_kernel(
    const float4* __restrict__ nodev, const int* __restrict__ rowstart,
    const int* __restrict__ csr, float* __restrict__ p, float* __restrict__ q) {
    int t = threadIdx.x;
    int node = blockIdx.x * 16 + (t >> 4);
    if (node >= NN) return;
    int l = t & 15;
    int beg = rowstart[node], end = rowstart[node + 1];
    float pz = 0.f, qz = 0.f;
    for (int i = beg + l; i < end; i += 16) {
        float4 v = nodev[csr[i]];
        pz += v.x;
        qz += v.y;
    }
#pragma unroll
    for (int m = 8; m >= 1; m >>= 1) {
        pz += __shfl_xor(pz, m);
        qz += __shfl_xor(qz, m);
    }
    if (l == 0) {
        int deg = end - beg;
        float inv = 1.0f / (float)(deg > 0 ? deg : 1);
        float4 me = nodev[node];
        p[node] = me.z + pz * inv;
        q[node] = me.w + qz * inv;
    }
}

__global__ __launch_bounds__(256) void score_kernel(
    const int* __restrict__ psrc, const int* __restrict__ pdst,
    const int* __restrict__ nsrc, const int* __restrict__ ndst,
    const float* __restrict__ p, const float* __restrict__ q,
    const float* __restrict__ bp, float* __restrict__ out) {
    int i = blockIdx.x * blockDim.x + threadIdx.x;
    float b = bp[0];
    if (i < EPOS) {
        out[i] = p[psrc[i]] + q[pdst[i]] + b;
    } else if (i < EPOS + ENEG) {
        int j = i - EPOS;
        out[i] = p[nsrc[j]] + q[ndst[j]] + b;
    }
}

extern "C" void kernel_launch(void* const* d_in, const int* in_sizes, int n_in,
                              void* d_out, int out_size, void* d_ws, size_t ws_size,
                              hipStream_t stream) {
    const float* x    = (const float*)d_in[0];
    const int*   msrc = (const int*)d_in[1];
    const int*   mdst = (const int*)d_in[2];
    const int*   psrc = (const int*)d_in[3];
    const int*   pdst = (const int*)d_in[4];
    const int*   nsrc = (const int*)d_in[5];
    const int*   ndst = (const int*)d_in[6];
    const float* W1s  = (const float*)d_in[7];
    const float* W1n  = (const float*)d_in[8];
    const float* b1   = (const float*)d_in[9];
    const float* W2s  = (const float*)d_in[10];
    const float* W2n  = (const float*)d_in[11];
    const float* b2   = (const float*)d_in[12];
    const float* wp   = (const float*)d_in[13];
    const float* bp   = (const float*)d_in[14];

    char* ws = (char*)d_ws;
    int*   cc       = (int*)ws + I_CC;
    int*   boff     = (int*)ws + I_BOFF;
    int*   ccur     = (int*)ws + I_CCUR;
    int*   rowstart = (int*)ws + I_ROW;
    int*   csr_src  = (int*)ws + I_CSR;
    u64*   creg  = (u64*)(ws + B_CREG);
    bf16*  xb    = (bf16*)(ws + B_XB);
    bf16*  h1b   = (bf16*)(ws + B_H1);
    float4* nodev = (float4*)(ws + B_NV);
    bf16*  Wt1   = (bf16*)(ws + B_WT1);
    bf16*  Wt2   = (bf16*)(ws + B_WT2);
    float* p     = (float*)(ws + B_P);
    float* q     = (float*)(ws + B_Q);
    float* out   = (float*)d_out;

    hipMemsetAsync(cc, 0, 256 * sizeof(int), stream);

    convc_kernel<<<XCONV_BLOCKS + 256 + CBLK, 256, 0, stream>>>(
        x, xb, W1s, W1n, W2n, W2s, Wt1, Wt2, mdst, cc);
    cscan_kernel<<<1, 256, 0, stream>>>(cc, boff, ccur);
    bin_kernel<<<(EM + RPB - 1) / RPB, 256, 0, stream>>>(msrc, mdst, ccur, creg);
    binsort_kernel<<<NB, 256, 0, stream>>>(creg, boff, rowstart, csr_src);

    ggemm1_kernel<<<GEMM_GRID, 256, 0, stream>>>(xb, rowstart, csr_src, Wt1, b1, h1b);
    gemm2_kernel<<<GEMM_GRID, 256, 0, stream>>>(h1b, Wt2, b2, wp, nodev);
    gather2_kernel<<<(NN + 15) / 16, 256, 0, stream>>>(nodev, rowstart, csr_src, p, q);
    score_kernel<<<(EPOS + ENEG + 255) / 256, 256, 0, stream>>>(
        psrc, pdst, nsrc, ndst, p, q, bp, out);
}

// Round 11
// 231.335 us; speedup vs baseline: 1.2296x; 1.2296x over previous
//
#include <hip/hip_runtime.h>

// GraphSAGE 2-layer + edge scorer, MI355X.
// R11: best-of-R9/R10. The ggemm1 fusion REVERTED (serialized gather<->MFMA
// per tile: 111 us, occupancy 19%) -- back to R9's separate gather1 (massive
// wave-parallel, 4-edge ILP, bf16x8) + gemm1 (B-in-registers). KEPT R10's
// lean CSR build: convc (x/W convert + coarse hist in one grid) -> cscan ->
// bin -> binsort (builds rowstart + csr from its own bucket records).
// Kept: scalar gather2 via wp-dot commute (R7), B-in-registers GEMMs (R5),
// mean(h1[src])@W2n == mean((h1@W2n)[src]); score = p[src]+q[dst]+bp.

#define NN 50000
#define EM 800000
#define EPOS 200000
#define ENEG 200000
#define NB 196            // coarse buckets: 196*256 >= NN
#define RPB 4096          // records per bin/coarse block
#define CBLK 196          // coarse-hist blocks: 196*4096 >= EM
#define MTILES 3125       // 50000 / 16 exactly
#define GEMM_GRID 512
#define XCONV_BLOCKS 6250 // NN*128/4/256

typedef __bf16 bf16;
typedef bf16 bf16x4 __attribute__((ext_vector_type(4)));
typedef bf16 bf16x8 __attribute__((ext_vector_type(8)));
typedef float floatx4 __attribute__((ext_vector_type(4)));
typedef unsigned long long u64;

// ---- workspace offsets ----
// int-word offsets:
#define I_CC   0             // 256 (coarse counts; memset 1 KB)
#define I_BOFF 256           // 512 (entries 0..NB)
#define I_CCUR 768           // 256
#define I_ROW  1024          // 50432 -> ends 51456
#define I_CSR  51456         // 800000 -> ends 851456
// byte offsets:
#define B_CREG 3405824       // 800000 * 8B (6.4 MB)
#define B_XB   9805824       // 6.4M bf16 (12.8 MB)
#define B_AGG1 22605824      // 6.4M bf16 (12.8 MB)
#define B_H1   35405824      // 12.8M bf16 (25.6 MB)
#define B_NV   61005824      // 50000 float4 (800 KB)
#define B_WT1  61805824      // 65536 bf16
#define B_WT2  61936896      // 65536 bf16
#define B_P    62067968      // 50176 fp32
#define B_Q    62268672      // 50176 fp32
// end ~62.5 MB

// fused conversions + coarse histogram.
__global__ __launch_bounds__(256) void convc_kernel(
    const float* __restrict__ x, bf16* __restrict__ xb,
    const float* __restrict__ W1s, const float* __restrict__ W1n,
    const float* __restrict__ W2n, const float* __restrict__ W2s,
    bf16* __restrict__ Wt1, bf16* __restrict__ Wt2,
    const int* __restrict__ mdst, int* __restrict__ cc) {
    if (blockIdx.x < XCONV_BLOCKS) {
        int i = blockIdx.x * 256 + threadIdx.x;
        float4 v = ((const float4*)x)[i];
        bf16x4 o;
        o[0] = (bf16)v.x; o[1] = (bf16)v.y; o[2] = (bf16)v.z; o[3] = (bf16)v.w;
        *(bf16x4*)(xb + (size_t)i * 4) = o;
    } else if (blockIdx.x < XCONV_BLOCKS + 256) {
        int i = (blockIdx.x - XCONV_BLOCKS) * 256 + threadIdx.x;
        int n = i >> 8, k = i & 255;
        float w1 = (k < 128) ? W1s[k * 256 + n] : W1n[(k - 128) * 256 + n];
        Wt1[i] = (bf16)w1;
        float w2 = (n < 128) ? W2n[k * 128 + n] : W2s[k * 128 + (n - 128)];
        Wt2[i] = (bf16)w2;
    } else {
        __shared__ int h[NB];
        int t = threadIdx.x;
        int cb = blockIdx.x - (XCONV_BLOCKS + 256);
        for (int i = t; i < NB; i += 256) h[i] = 0;
        __syncthreads();
        int e0 = cb * RPB;
        int nrec = EM - e0; if (nrec > RPB) nrec = RPB;
        for (int j = t; j < nrec; j += 256) atomicAdd(&h[mdst[e0 + j] >> 8], 1);
        __syncthreads();
        if (t < NB && h[t] > 0) atomicAdd(&cc[t], h[t]);
    }
}

// 1-block scan of the NB coarse counts -> boff (exclusive, +sentinel), ccur.
__global__ __launch_bounds__(256) void cscan_kernel(const int* __restrict__ cc,
                                                    int* __restrict__ boff,
                                                    int* __restrict__ ccur) {
    __shared__ int s[256];
    int t = threadIdx.x;
    s[t] = (t < NB) ? cc[t] : 0;
    __syncthreads();
    for (int o = 1; o < 256; o <<= 1) {
        int u = (t >= o) ? s[t - o] : 0;
        __syncthreads();
        s[t] += u;
        __syncthreads();
    }
    int excl = (t == 0) ? 0 : s[t - 1];
    if (t < NB) { boff[t] = excl; ccur[t] = excl; }
    if (t == 0) boff[NB] = EM;
}

// pass A: LDS-sort 4096 edges by coarse bucket (dst>>8), flush bucket-grouped
// 8B (src,dst) records into per-bucket regions of creg.
__global__ __launch_bounds__(256) void bin_kernel(const int* __restrict__ src,
                                                  const int* __restrict__ dst,
                                                  int* __restrict__ ccur,
                                                  u64* __restrict__ creg) {
    __shared__ int hist[NB];
    __shared__ int cnt2[NB];
    __shared__ int goff[NB];
    __shared__ int base[256];
    __shared__ u64 sorted[RPB];
    int t = threadIdx.x;
    int e0 = blockIdx.x * RPB;
    int nrec = EM - e0; if (nrec > RPB) nrec = RPB;

    for (int i = t; i < NB; i += 256) { hist[i] = 0; cnt2[i] = 0; }
    __syncthreads();

    int myb[RPB / 256];
    u64 myrec[RPB / 256];
#pragma unroll
    for (int j = 0; j < RPB / 256; ++j) {
        int idx = j * 256 + t;
        if (idx < nrec) {
            int s = src[e0 + idx], d = dst[e0 + idx];
            myb[j] = d >> 8;
            myrec[j] = ((u64)(unsigned)d << 32) | (unsigned)s;
            atomicAdd(&hist[myb[j]], 1);
        } else myb[j] = -1;
    }
    __syncthreads();

    base[t] = (t < NB) ? hist[t] : 0;
    __syncthreads();
    for (int o = 1; o < 256; o <<= 1) {
        int u = (t >= o) ? base[t - o] : 0;
        __syncthreads();
        base[t] += u;
        __syncthreads();
    }

    if (t < NB && hist[t] > 0) goff[t] = atomicAdd(&ccur[t], hist[t]);
#pragma unroll
    for (int j = 0; j < RPB / 256; ++j) {
        if (myb[j] >= 0) {
            int rk = atomicAdd(&cnt2[myb[j]], 1);
            sorted[base[myb[j]] - hist[myb[j]] + rk] = myrec[j];
        }
    }
    __syncthreads();

#pragma unroll
    for (int j = 0; j < RPB / 256; ++j) {
        int idx = j * 256 + t;
        if (idx < nrec) {
            u64 rec = sorted[idx];
            int b = (int)(rec >> 40);
            int exb = base[b] - hist[b];
            creg[(size_t)goff[b] + (idx - exb)] = rec;
        }
    }
}

// pass B: one block per bucket. Builds rowstart for its 256 nodes from its
// own records (LDS hist + scan) AND places edges into csr via LDS cursors.
__global__ __launch_bounds__(256) void binsort_kernel(
    const u64* __restrict__ creg, const int* __restrict__ boff,
    int* __restrict__ rowstart, int* __restrict__ csr) {
    __shared__ int lcnt[256];
    __shared__ int sc[256];
    __shared__ int lcur[256];
    int b = blockIdx.x, t = threadIdx.x;
    int beg = boff[b], end = boff[b + 1];
    lcnt[t] = 0;
    __syncthreads();
    for (int i = beg + t; i < end; i += 256) {
        int d = (int)(creg[i] >> 32);
        atomicAdd(&lcnt[d & 255], 1);
    }
    __syncthreads();
    sc[t] = lcnt[t];
    __syncthreads();
    for (int o = 1; o < 256; o <<= 1) {
        int u = (t >= o) ? sc[t - o] : 0;
        __syncthreads();
        sc[t] += u;
        __syncthreads();
    }
    int excl = beg + sc[t] - lcnt[t];
    int node = b * 256 + t;
    if (node < NN) rowstart[node] = excl;
    if (b == NB - 1 && t == 0) rowstart[NN] = EM;
    lcur[t] = excl;
    __syncthreads();
    for (int i = beg + t; i < end; i += 256) {
        u64 rec = creg[i];
        int d = (int)(rec >> 32);
        int pos = atomicAdd(&lcur[d & 255], 1);
        csr[pos] = (int)(rec & 0xffffffffu);
    }
}

// one wave per node, 4 edges in flight (quad-parallel), bf16x8 per lane.
__global__ __launch_bounds__(256) void gather1_kernel(const bf16* __restrict__ feat,
                                                      const int* __restrict__ rowstart,
                                                      const int* __restrict__ csr,
                                                      bf16* __restrict__ agg) {
    int node = (blockIdx.x * 256 + threadIdx.x) >> 6;
    if (node >= NN) return;
    int lane = threadIdx.x & 63;
    int q = lane >> 4, r = lane & 15;
    int c = r * 8;
    int beg = rowstart[node], end = rowstart[node + 1];
    float acc[8] = {0.f, 0.f, 0.f, 0.f, 0.f, 0.f, 0.f, 0.f};
    for (int i = beg + q; i < end; i += 4) {
        int s = csr[i];
        bf16x8 v = *(const bf16x8*)(feat + (size_t)s * 128 + c);
#pragma unroll
        for (int u = 0; u < 8; ++u) acc[u] += (float)v[u];
    }
#pragma unroll
    for (int m = 16; m <= 32; m <<= 1)
#pragma unroll
        for (int u = 0; u < 8; ++u) acc[u] += __shfl_xor(acc[u], m);
    if (q == 0) {
        int deg = end - beg;
        float inv = 1.0f / (float)(deg > 0 ? deg : 1);
        bf16x8 o;
#pragma unroll
        for (int u = 0; u < 8; ++u) o[u] = (bf16)(acc[u] * inv);
        *(bf16x8*)(agg + (size_t)node * 128 + c) = o;
    }
}

// h1 = relu([xb | agg1b] @ Wt1^T + b1) -> bf16. B in registers, A streamed.
__global__ __launch_bounds__(256) void gemm1_kernel(
    const bf16* __restrict__ xb, const bf16* __restrict__ aggb,
    const bf16* __restrict__ Wt, const float* __restrict__ b1,
    bf16* __restrict__ h1b) {
    int w = threadIdx.x >> 6;
    int lane = threadIdx.x & 63;
    int r = lane & 15, quad = lane >> 4;
    int colbase = w * 64;

    bf16x8 bfr[4][8];
#pragma unroll
    for (int t = 0; t < 4; ++t)
#pragma unroll
        for (int kk = 0; kk < 8; ++kk)
            bfr[t][kk] = *(const bf16x8*)(Wt + (size_t)(colbase + t * 16 + r) * 256
                                          + kk * 32 + quad * 8);
    float bb[4];
#pragma unroll
    for (int t = 0; t < 4; ++t) bb[t] = b1[colbase + t * 16 + r];

    for (int tile = blockIdx.x; tile < MTILES; tile += GEMM_GRID) {
        int m0 = tile * 16;
        int row = m0 + r;
        bf16x8 a[8];
#pragma unroll
        for (int kk = 0; kk < 4; ++kk)
            a[kk] = *(const bf16x8*)(xb + (size_t)row * 128 + kk * 32 + quad * 8);
#pragma unroll
        for (int kk = 4; kk < 8; ++kk)
            a[kk] = *(const bf16x8*)(aggb + (size_t)row * 128 + (kk - 4) * 32 + quad * 8);
        floatx4 acc[4];
#pragma unroll
        for (int t = 0; t < 4; ++t) acc[t] = (floatx4){0.f, 0.f, 0.f, 0.f};
#pragma unroll
        for (int kk = 0; kk < 8; ++kk)
#pragma unroll
            for (int t = 0; t < 4; ++t)
                acc[t] = __builtin_amdgcn_mfma_f32_16x16x32_bf16(a[kk], bfr[t][kk],
                                                                 acc[t], 0, 0, 0);
        int mb = m0 + quad * 4;
#pragma unroll
        for (int t = 0; t < 4; ++t) {
            int col = colbase + t * 16 + r;
#pragma unroll
            for (int rr = 0; rr < 4; ++rr) {
                float v = acc[t][rr] + bb[t];
                v = v > 0.f ? v : 0.f;
                h1b[(size_t)(mb + rr) * 256 + col] = (bf16)v;
            }
        }
    }
}

// Fused gemm2: nodev[n] = {zp, zq, ps, qs}; zp=(h1@W2n)[n].wp[:128] etc.
__global__ __launch_bounds__(256) void gemm2_kernel(
    const bf16* __restrict__ h1b, const bf16* __restrict__ Wt,
    const float* __restrict__ b2, const float* __restrict__ wp,
    float4* __restrict__ nodev) {
    __shared__ float lp[4][16];
    __shared__ float lq[4][16];
    int w = threadIdx.x >> 6;
    int lane = threadIdx.x & 63;
    int r = lane & 15, quad = lane >> 4;
    int colbase = w * 64;

    bf16x8 bfr[4][8];
#pragma unroll
    for (int t = 0; t < 4; ++t)
#pragma unroll
        for (int kk = 0; kk < 8; ++kk)
            bfr[t][kk] = *(const bf16x8*)(Wt + (size_t)(colbase + t * 16 + r) * 256
                                          + kk * 32 + quad * 8);
    float bb[4], wA[4], wB[4];
#pragma unroll
    for (int t = 0; t < 4; ++t) {
        int col = colbase + t * 16 + r;
        if (w < 2) {
            bb[t] = 0.f;
            wA[t] = wp[col];
            wB[t] = wp[128 + col];
        } else {
            int c2 = col - 128;
            bb[t] = b2[c2];
            wA[t] = wp[c2];
            wB[t] = wp[128 + c2];
        }
    }

    for (int tile = blockIdx.x; tile < MTILES; tile += GEMM_GRID) {
        int m0 = tile * 16;
        int row = m0 + r;
        bf16x8 a[8];
#pragma unroll
        for (int kk = 0; kk < 8; ++kk)
            a[kk] = *(const bf16x8*)(h1b + (size_t)row * 256 + kk * 32 + quad * 8);
        floatx4 acc[4];
#pragma unroll
        for (int t = 0; t < 4; ++t) acc[t] = (floatx4){0.f, 0.f, 0.f, 0.f};
#pragma unroll
        for (int kk = 0; kk < 8; ++kk)
#pragma unroll
            for (int t = 0; t < 4; ++t)
                acc[t] = __builtin_amdgcn_mfma_f32_16x16x32_bf16(a[kk], bfr[t][kk],
                                                                 acc[t], 0, 0, 0);
        float pacc[4], qacc[4];
#pragma unroll
        for (int rr = 0; rr < 4; ++rr) {
            float pr = 0.f, qr = 0.f;
#pragma unroll
            for (int t = 0; t < 4; ++t) {
                float v = acc[t][rr] + bb[t];
                pr += v * wA[t];
                qr += v * wB[t];
            }
            pacc[rr] = pr;
            qacc[rr] = qr;
        }
#pragma unroll
        for (int m = 1; m <= 8; m <<= 1) {
#pragma unroll
            for (int rr = 0; rr < 4; ++rr) {
                pacc[rr] += __shfl_xor(pacc[rr], m);
                qacc[rr] += __shfl_xor(qacc[rr], m);
            }
        }
        if (r == 0) {
#pragma unroll
            for (int rr = 0; rr < 4; ++rr) {
                lp[w][quad * 4 + rr] = pacc[rr];
                lq[w][quad * 4 + rr] = qacc[rr];
            }
        }
        __syncthreads();
        if (threadIdx.x < 16) {
            int rw = threadIdx.x;
            float4 o;
            o.x = lp[0][rw] + lp[1][rw];
            o.y = lq[0][rw] + lq[1][rw];
            o.z = lp[2][rw] + lp[3][rw];
            o.w = lq[2][rw] + lq[3][rw];
            nodev[m0 + rw] = o;
        }
        __syncthreads();
    }
}

// scalar gather: p[n] = ps[n] + mean(zp[src]); q likewise. nodev is 800 KB.
__global__ __launch_bounds__(256) void gather2_kernel(
    const float4* __restrict__ nodev, const int* __restrict__ rowstart,
    const int* __restrict__ csr, float* __restrict__ p, float* __restrict__ q) {
    int t = threadIdx.x;
    int node = blockIdx.x * 16 + (t >> 4);
    if (node >= NN) return;
    int l = t & 15;
    int beg = rowstart[node], end = rowstart[node + 1];
    float pz = 0.f, qz = 0.f;
    for (int i = beg + l; i < end; i += 16) {
        float4 v = nodev[csr[i]];
        pz += v.x;
        qz += v.y;
    }
#pragma unroll
    for (int m = 8; m >= 1; m >>= 1) {
        pz += __shfl_xor(pz, m);
        qz += __shfl_xor(qz, m);
    }
    if (l == 0) {
        int deg = end - beg;
        float inv = 1.0f / (float)(deg > 0 ? deg : 1);
        float4 me = nodev[node];
        p[node] = me.z + pz * inv;
        q[node] = me.w + qz * inv;
    }
}

__global__ __launch_bounds__(256) void score_kernel(
    const int* __restrict__ psrc, const int* __restrict__ pdst,
    const int* __restrict__ nsrc, const int* __restrict__ ndst,
    const float* __restrict__ p, const float* __restrict__ q,
    const float* __restrict__ bp, float* __restrict__ out) {
    int i = blockIdx.x * blockDim.x + threadIdx.x;
    float b = bp[0];
    if (i < EPOS) {
        out[i] = p[psrc[i]] + q[pdst[i]] + b;
    } else if (i < EPOS + ENEG) {
        int j = i - EPOS;
        out[i] = p[nsrc[j]] + q[ndst[j]] + b;
    }
}

extern "C" void kernel_launch(void* const* d_in, const int* in_sizes, int n_in,
                              void* d_out, int out_size, void* d_ws, size_t ws_size,
                              hipStream_t stream) {
    const float* x    = (const float*)d_in[0];
    const int*   msrc = (const int*)d_in[1];
    const int*   mdst = (const int*)d_in[2];
    const int*   psrc = (const int*)d_in[3];
    const int*   pdst = (const int*)d_in[4];
    const int*   nsrc = (const int*)d_in[5];
    const int*   ndst = (const int*)d_in[6];
    const float* W1s  = (const float*)d_in[7];
    const float* W1n  = (const float*)d_in[8];
    const float* b1   = (const float*)d_in[9];
    const float* W2s  = (const float*)d_in[10];
    const float* W2n  = (const float*)d_in[11];
    const float* b2   = (const float*)d_in[12];
    const float* wp   = (const float*)d_in[13];
    const float* bp   = (const float*)d_in[14];

    char* ws = (char*)d_ws;
    int*   cc       = (int*)ws + I_CC;
    int*   boff     = (int*)ws + I_BOFF;
    int*   ccur     = (int*)ws + I_CCUR;
    int*   rowstart = (int*)ws + I_ROW;
    int*   csr_src  = (int*)ws + I_CSR;
    u64*   creg  = (u64*)(ws + B_CREG);
    bf16*  xb    = (bf16*)(ws + B_XB);
    bf16*  agg1b = (bf16*)(ws + B_AGG1);
    bf16*  h1b   = (bf16*)(ws + B_H1);
    float4* nodev = (float4*)(ws + B_NV);
    bf16*  Wt1   = (bf16*)(ws + B_WT1);
    bf16*  Wt2   = (bf16*)(ws + B_WT2);
    float* p     = (float*)(ws + B_P);
    float* q     = (float*)(ws + B_Q);
    float* out   = (float*)d_out;

    hipMemsetAsync(cc, 0, 256 * sizeof(int), stream);

    convc_kernel<<<XCONV_BLOCKS + 256 + CBLK, 256, 0, stream>>>(
        x, xb, W1s, W1n, W2n, W2s, Wt1, Wt2, mdst, cc);
    cscan_kernel<<<1, 256, 0, stream>>>(cc, boff, ccur);
    bin_kernel<<<(EM + RPB - 1) / RPB, 256, 0, stream>>>(msrc, mdst, ccur, creg);
    binsort_kernel<<<NB, 256, 0, stream>>>(creg, boff, rowstart, csr_src);

    gather1_kernel<<<(NN + 3) / 4, 256, 0, stream>>>(xb, rowstart, csr_src, agg1b);
    gemm1_kernel<<<GEMM_GRID, 256, 0, stream>>>(xb, agg1b, Wt1, b1, h1b);
    gemm2_kernel<<<GEMM_GRID, 256, 0, stream>>>(h1b, Wt2, b2, wp, nodev);
    gather2_kernel<<<(NN + 15) / 16, 256, 0, stream>>>(nodev, rowstart, csr_src, p, q);
    score_kernel<<<(EPOS + ENEG + 255) / 256, 256, 0, stream>>>(
        psrc, pdst, nsrc, ndst, p, q, bp, out);
}